// Round 14
// baseline (212.506 us; speedup 1.0000x reference)
//
#include <hip/hip_runtime.h>
#include <hip/hip_bf16.h>

namespace {

constexpr int kB = 2, kS = 13125, kD = 256, kH = 8, kL = 3, kP = 4, kFFN = 1024, kDh = 32;
constexpr int kM = kB * kS;  // 26250

typedef __attribute__((ext_vector_type(8))) short short8v;
typedef __attribute__((ext_vector_type(4))) float f32x4;
typedef __attribute__((ext_vector_type(2))) float f32x2;
typedef __attribute__((ext_vector_type(2))) unsigned int uint2v;

__device__ __forceinline__ float bf2f(unsigned short u) {
  unsigned int x = ((unsigned int)u) << 16;
  return __builtin_bit_cast(float, x);
}
__device__ __forceinline__ unsigned short f2bf(float f) {
  unsigned int u = __builtin_bit_cast(unsigned int, f);
  u += 0x7FFFu + ((u >> 16) & 1u);  // RNE
  return (unsigned short)(u >> 16);
}

__device__ __forceinline__ void gload_lds16(const void* g, void* l) {
  __builtin_amdgcn_global_load_lds(
      (const __attribute__((address_space(1))) unsigned int*)g,
      (__attribute__((address_space(3))) unsigned int*)l, 16, 0, 0);
}

// ---------------- merged weight prep (one launch for all 5 matrices) --------
__global__ __launch_bounds__(256) void wprep_all(const float* __restrict__ Wv,
                                                 const float* __restrict__ Wo,
                                                 const float* __restrict__ Woff,
                                                 const float* __restrict__ Wattn,
                                                 const float* __restrict__ boff,
                                                 const float* __restrict__ battn,
                                                 const float* __restrict__ W1,
                                                 const float* __restrict__ W2,
                                                 unsigned short* __restrict__ Wvt,
                                                 unsigned short* __restrict__ Wot,
                                                 unsigned short* __restrict__ Wct,
                                                 float* __restrict__ bcomb,
                                                 unsigned short* __restrict__ W1t,
                                                 unsigned short* __restrict__ W2t) {
  int idx = blockIdx.x * 256 + threadIdx.x;
  if (idx < 65536) {                       // Wvt: [256n][256k]
    int n = idx >> 8, k = idx & 255;
    Wvt[idx] = f2bf(Wv[k * 256 + n]);
  } else if (idx < 131072) {               // Wot
    int j = idx - 65536;
    int n = j >> 8, k = j & 255;
    Wot[j] = f2bf(Wo[k * 256 + n]);
  } else if (idx < 204800) {               // Wct: 288 x 256, per-head interleave
    int j = idx - 131072;
    int n = j >> 8, k = j & 255;
    int h = n / 36, jj = n - h * 36;
    float v = (jj < 24) ? Woff[(size_t)k * 192 + h * 24 + jj]
                        : Wattn[(size_t)k * 96 + h * 12 + (jj - 24)];
    Wct[j] = f2bf(v);
    if (j < 288) {
      int hh = j / 36, q = j - hh * 36;
      bcomb[j] = (q < 24) ? boff[hh * 24 + q] : battn[hh * 12 + (q - 24)];
    }
  } else if (idx < 466944) {               // W1t: 1024 x 256
    int j = idx - 204800;
    int n = j >> 8, k = j & 255;
    W1t[j] = f2bf(W1[(size_t)k * 1024 + n]);
  } else if (idx < 729088) {               // W2t: 256 x 1024 (K=1024)
    int j = idx - 466944;
    int n = j >> 10, k = j & 1023;
    W2t[j] = f2bf(W2[(size_t)k * 256 + n]);
  }
}

// ---------------- xb = bf16(x); qb = bf16(x + pos)  (x read once) ----------
__global__ __launch_bounds__(256) void prep_kernel(const float4* __restrict__ x,
                                                   const float4* __restrict__ pos,
                                                   ushort4* __restrict__ xb,
                                                   ushort4* __restrict__ qb, int n4) {
  int i = blockIdx.x * 256 + threadIdx.x;
  if (i < n4) {
    float4 a = x[i], b = pos[i];
    xb[i] = make_ushort4(f2bf(a.x), f2bf(a.y), f2bf(a.z), f2bf(a.w));
    qb[i] = make_ushort4(f2bf(a.x + b.x), f2bf(a.y + b.y),
                         f2bf(a.z + b.z), f2bf(a.w + b.w));
  }
}

// ---------------- bf16 MFMA GEMM body (device fn, proven structure) ---------
template <int EPI, bool OBF, bool VHM>
__device__ __forceinline__ void gemm_body(const unsigned short* __restrict__ A,
                                          const unsigned short* __restrict__ Bt,
                                          const float* __restrict__ bias,
                                          void* __restrict__ Cp,
                                          int M, int N, int K, int bx, int by,
                                          unsigned short* smem) {
  constexpr int MI = 2;
  constexpr int BM = 64;
  unsigned short* As = smem;
  unsigned short* Bs = smem + BM * 32;
  const int tid = threadIdx.x;
  const int w = tid >> 6, lane = tid & 63;
  const int m0 = by * BM, n0 = bx * 128;
  const int wr = w >> 1, wc = w & 1;
  const int r_ = lane >> 2, sl = lane & 3;

  f32x4 acc[MI][4] = {};

  for (int k0 = 0; k0 < K; k0 += 32) {
    {
      const int row = w * 16 + r_;
      const int sg = sl ^ ((row >> 1) & 3);
      int arow = m0 + row;
      arow = arow < M ? arow : M - 1;
      gload_lds16(A + (size_t)arow * K + k0 + sg * 8, &As[(w * 16) * 32]);
    }
#pragma unroll
    for (int i = 0; i < 2; ++i) {
      const int row = i * 64 + w * 16 + r_;
      const int sg = sl ^ ((row >> 1) & 3);
      gload_lds16(Bt + (size_t)(n0 + row) * K + k0 + sg * 8, &Bs[(i * 64 + w * 16) * 32]);
    }
    __syncthreads();
    short8v a[MI], b[4];
#pragma unroll
    for (int mi = 0; mi < MI; ++mi) {
      const int row = wr * (MI * 16) + mi * 16 + (lane & 15);
      const int slot = (lane >> 4) ^ ((row >> 1) & 3);
      a[mi] = *(const short8v*)&As[row * 32 + slot * 8];
    }
#pragma unroll
    for (int ni = 0; ni < 4; ++ni) {
      const int row = wc * 64 + ni * 16 + (lane & 15);
      const int slot = (lane >> 4) ^ ((row >> 1) & 3);
      b[ni] = *(const short8v*)&Bs[row * 32 + slot * 8];
    }
#pragma unroll
    for (int mi = 0; mi < MI; ++mi)
#pragma unroll
      for (int ni = 0; ni < 4; ++ni)
        acc[mi][ni] = __builtin_amdgcn_mfma_f32_16x16x32_bf16(a[mi], b[ni], acc[mi][ni], 0, 0, 0);
    __syncthreads();
  }

  const int cr = lane >> 4, cc = lane & 15;
  if (OBF) {
    unsigned short* Cs = smem;  // 64 rows x 128 cols, chunk-XOR swizzled
#pragma unroll
    for (int ni = 0; ni < 4; ++ni) {
      const int col = wc * 64 + ni * 16 + cc;
      const float bv = bias[n0 + col];
#pragma unroll
      for (int mi = 0; mi < MI; ++mi)
#pragma unroll
        for (int r = 0; r < 4; ++r) {
          const int loc = wr * (MI * 16) + mi * 16 + cr * 4 + r;
          float v = acc[mi][ni][r] + bv;
          if (EPI == 2) v = fmaxf(v, 0.f);
          const int ch = (col >> 3) ^ (loc & 7);
          Cs[loc * 128 + ch * 8 + (col & 7)] = f2bf(v);
        }
    }
    __syncthreads();
    const int lr = tid >> 4, lc = tid & 15;
#pragma unroll
    for (int pp = 0; pp < 4; ++pp) {
      const int loc = pp * 16 + lr;
      const int grow = m0 + loc;
      const short8v vv = *(const short8v*)&Cs[loc * 128 + ((lc ^ (loc & 7)) * 8)];
      if (grow < M) {
        if (VHM) {
          const int col = n0 + lc * 8;
          const int bb = grow >= kS ? 1 : 0;
          const int ss = grow - bb * kS;
          const int hh = col >> 5;
          *(short8v*)((unsigned short*)Cp +
                      (((size_t)(bb * kH + hh) * kS + ss) * kDh + (col & 31))) = vv;
        } else {
          *(short8v*)((unsigned short*)Cp + (size_t)grow * N + n0 + lc * 8) = vv;
        }
      }
    }
    __syncthreads();
  } else {
#pragma unroll
    for (int ni = 0; ni < 4; ++ni) {
      const int col = n0 + wc * 64 + ni * 16 + cc;
      if (col >= N) continue;
      const float bv = bias[col];
#pragma unroll
      for (int mi = 0; mi < MI; ++mi) {
#pragma unroll
        for (int r = 0; r < 4; ++r) {
          const int row = m0 + wr * (MI * 16) + mi * 16 + cr * 4 + r;
          if (row >= M) continue;
          ((float*)Cp)[(size_t)row * N + col] = acc[mi][ni][r] + bv;
        }
      }
    }
  }
}

// generic single-GEMM wrapper (used for aob)
template <int EPI, bool OBF, bool VHM>
__global__ __launch_bounds__(256) void mfma_gemm(const unsigned short* __restrict__ A,
                                                 const unsigned short* __restrict__ Bt,
                                                 const float* __restrict__ bias,
                                                 void* __restrict__ Cp,
                                                 int M, int N, int K) {
  __shared__ unsigned short smem[2 * 128 * 32];
  gemm_body<EPI, OBF, VHM>(A, Bt, bias, Cp, M, N, K, blockIdx.x, blockIdx.y, smem);
}

// merged value+oa GEMM: grid (5, mt64). bx<2 -> value (bf16 head-major),
// bx>=2 -> oa (f32).
__global__ __launch_bounds__(256) void qkvoa_gemm(const unsigned short* __restrict__ xb,
                                                  const unsigned short* __restrict__ Wvt,
                                                  const float* __restrict__ bval,
                                                  unsigned short* __restrict__ value,
                                                  const unsigned short* __restrict__ qb,
                                                  const unsigned short* __restrict__ Wct,
                                                  const float* __restrict__ bcomb,
                                                  float* __restrict__ oa,
                                                  int M) {
  __shared__ unsigned short smem[2 * 128 * 32];
  if (blockIdx.x < 2) {
    gemm_body<0, true, true>(xb, Wvt, bval, value, M, 256, 256, blockIdx.x, blockIdx.y, smem);
  } else {
    gemm_body<0, false, false>(qb, Wct, bcomb, oa, M, 288, 256, blockIdx.x - 2, blockIdx.y, smem);
  }
}

// ---------------- fused FFN v8: v4 dataflow + dedup'd stage-1 LDS reads -----
// Waves re-partitioned as (ffn-half fh = w&1) x (m-half mh = w>>1); each wave
// holds TWO A m-frags (areg[2][8]) so every stage-1 W1 read feeds 2 MFMAs.
// Stage-1 reads/block-jt: 128 -> 64 (v4 had all 4 waves reading identical W1
// fragments). P write uses v4's exact slot formula (kb=ffn>>5, slot=
// ffn_local>>3, 8B ds_write_b64, same XOR) so stage-2 stays byte-identical
// to the proven v4 path. Numerics bitwise identical to v4.
__global__ __launch_bounds__(256) void ffn_fused(const unsigned short* __restrict__ Ain,
                                                 const unsigned short* __restrict__ W1t,
                                                 const unsigned short* __restrict__ W2t,
                                                 const float* __restrict__ b1,
                                                 const float* __restrict__ b2,
                                                 unsigned short* __restrict__ Cp,
                                                 int M) {
  __shared__ unsigned short W1s[2][64 * 256];  // 2 x 32 KB, [kk][row][32] swizzled
  __shared__ unsigned short Ps[2 * 64 * 32];   // 8 KB, [kb][m(64)][32] swizzled
  const int tid = threadIdx.x;
  const int w = tid >> 6, lane = tid & 63;
  const int m0 = blockIdx.x * 64;
  const int cr = lane >> 4, cc = lane & 15;
  const int fh = w & 1;   // stage-1 ffn half (32 rows)
  const int mh = w >> 1;  // stage-1 m half (2 frags)

  // areg[mi][kk] = A[m0 + (mh*2+mi)*16 + cc][kk*32 + cr*8 ..+8]
  short8v areg[2][8];
#pragma unroll
  for (int mi = 0; mi < 2; ++mi) {
    int grow = m0 + (mh * 2 + mi) * 16 + cc;
    grow = grow < M ? grow : M - 1;
    const unsigned short* ap = Ain + (size_t)grow * 256 + cr * 8;
#pragma unroll
    for (int kk = 0; kk < 8; ++kk) areg[mi][kk] = *(const short8v*)(ap + kk * 32);
  }

  auto stage_w1 = [&](int jt, int buf) {
    const unsigned short* src = W1t + (size_t)jt * 64 * 256;
#pragma unroll
    for (int it = 0; it < 8; ++it) {
      const int idx = it * 256 + tid;
      const int kk = idx >> 8;
      const int row = (idx >> 2) & 63;
      const int sl = idx & 3;
      const int ssl = sl ^ ((row >> 1) & 3);
      gload_lds16(src + (size_t)row * 256 + kk * 32 + ssl * 8, &W1s[buf][idx * 8]);
    }
  };

  f32x4 acc[4][4] = {};  // [mi][ni]: rows mi*16+cr*4+r, cols w*64+ni*16+cc

  stage_w1(0, 0);
  __syncthreads();

  for (int jt = 0; jt < 16; ++jt) {
    const int buf = jt & 1;
    if (jt < 15) stage_w1(jt + 1, buf ^ 1);

    // hoist this jt's W2 fragments into registers (overlap stage-1)
    short8v w2f[8];
#pragma unroll
    for (int kk2 = 0; kk2 < 2; ++kk2)
#pragma unroll
      for (int ni = 0; ni < 4; ++ni)
        w2f[kk2 * 4 + ni] = *(const short8v*)(W2t +
            (size_t)(w * 64 + ni * 16 + cc) * 1024 + jt * 64 + kk2 * 32 + cr * 8);

    // ---- stage 1: one W1 read feeds TWO MFMAs (areg[0], areg[1])
    f32x4 p1[2][2] = {};  // [lf][mi]
#pragma unroll
    for (int kk = 0; kk < 8; ++kk) {
#pragma unroll
      for (int lf = 0; lf < 2; ++lf) {
        const int row = fh * 32 + lf * 16 + cc;
        const short8v wv = *(const short8v*)
            &W1s[buf][kk * 2048 + row * 32 + ((cr ^ ((row >> 1) & 3)) * 8)];
        p1[lf][0] = __builtin_amdgcn_mfma_f32_16x16x32_bf16(wv, areg[0][kk], p1[lf][0], 0, 0, 0);
        p1[lf][1] = __builtin_amdgcn_mfma_f32_16x16x32_bf16(wv, areg[1][kk], p1[lf][1], 0, 0, 0);
      }
    }
    // bias + relu + bf16-pack -> Ps, v4's exact slot formula.
    // lane holds P[ffn = fh*32 + lf*16 + cr*4 + r][m = (mh*2+mi)*16 + cc]
#pragma unroll
    for (int lf = 0; lf < 2; ++lf) {
      const float4 bv = *(const float4*)&b1[jt * 64 + fh * 32 + lf * 16 + cr * 4];
#pragma unroll
      for (int mi = 0; mi < 2; ++mi) {
        const int mrow = (mh * 2 + mi) * 16 + cc;
        const int rsw = (mrow >> 1) & 3;
        const unsigned int u0 =
            (unsigned)f2bf(fmaxf(p1[lf][mi][0] + bv.x, 0.f)) |
            ((unsigned)f2bf(fmaxf(p1[lf][mi][1] + bv.y, 0.f)) << 16);
        const unsigned int u1 =
            (unsigned)f2bf(fmaxf(p1[lf][mi][2] + bv.z, 0.f)) |
            ((unsigned)f2bf(fmaxf(p1[lf][mi][3] + bv.w, 0.f)) << 16);
        const int slot = lf * 2 + (cr >> 1);
        uint2v* dst = (uint2v*)&Ps[fh * 2048 + mrow * 32 + ((slot ^ rsw) * 8) + (cr & 1) * 4];
        *dst = (uint2v){u0, u1};
      }
    }
    __syncthreads();  // Ps visible; drains W1 prefetch

    // ---- stage 2 (byte-identical to v4): acc += P @ W2
#pragma unroll
    for (int kk2 = 0; kk2 < 2; ++kk2) {
      short8v pf[4];
#pragma unroll
      for (int mi = 0; mi < 4; ++mi) {
        const int row = mi * 16 + cc;
        pf[mi] = *(const short8v*)
            &Ps[kk2 * 2048 + row * 32 + ((cr ^ ((row >> 1) & 3)) * 8)];
      }
#pragma unroll
      for (int ni = 0; ni < 4; ++ni) {
#pragma unroll
        for (int mi = 0; mi < 4; ++mi)
          acc[mi][ni] = __builtin_amdgcn_mfma_f32_16x16x32_bf16(pf[mi], w2f[kk2 * 4 + ni],
                                                               acc[mi][ni], 0, 0, 0);
      }
    }
    __syncthreads();  // Ps reads done before next jt's writes
  }

  // epilogue: stage bf16 C tile into W1s[0] (reuse), then full-line stores
  unsigned short* Cs = &W1s[0][0];
#pragma unroll
  for (int ni = 0; ni < 4; ++ni) {
    const int col = w * 64 + ni * 16 + cc;
    const float bv = b2[col];
#pragma unroll
    for (int mi = 0; mi < 4; ++mi)
#pragma unroll
      for (int r = 0; r < 4; ++r) {
        const int row = mi * 16 + cr * 4 + r;
        const float v = acc[mi][ni][r] + bv;
        Cs[row * 256 + (((col >> 3) ^ (row & 7)) * 8) + (col & 7)] = f2bf(v);
      }
  }
  __syncthreads();
#pragma unroll
  for (int it = 0; it < 8; ++it) {
    const int row = it * 8 + (tid >> 5);
    const int grow = m0 + row;
    const int ch = tid & 31;
    const short8v vv = *(const short8v*)&Cs[row * 256 + ((ch ^ (row & 7)) * 8)];
    if (grow < M) *(short8v*)(Cp + (size_t)grow * 256 + ch * 8) = vv;
  }
}

// ---------------- deformable sampling (value head-major bf16 -> sv bf16) ----
__device__ __forceinline__ void acc2u(f32x2* acc, unsigned u, int i, float m) {
  f32x2 v;
  v.x = __builtin_bit_cast(float, u << 16);
  v.y = __builtin_bit_cast(float, u & 0xFFFF0000u);
  acc[i] += m * v;
}
__device__ __forceinline__ void acc_corner(f32x2* acc, uint4 q, float m) {
  acc2u(acc, q.x, 0, m);
  acc2u(acc, q.y, 1, m);
  acc2u(acc, q.z, 2, m);
  acc2u(acc, q.w, 3, m);
}

__global__ __launch_bounds__(256) void sample_kernel(const unsigned short* __restrict__ value,
                                                     const float* __restrict__ oa,
                                                     const float* __restrict__ refp,
                                                     unsigned short* __restrict__ out) {
  const int tid = threadIdx.x;
  const int sub = tid >> 2;    // 64 queries per block
  const int lane = tid & 3;    // 4 lanes x 8 channels
  const int gi = blockIdx.x * 64 + sub;  // index over B*S*H
  if (gi >= kB * kS * kH) return;
  const int h = gi & 7;
  const int bs = gi >> 3;
  const int b = (bs >= kS) ? 1 : 0;  // kB == 2

  const float* op = oa + (size_t)bs * 288 + h * 36;
  const float* al = op + 24;
  float w[12];
  float mx = -1e30f;
#pragma unroll
  for (int i = 0; i < 12; ++i) { w[i] = al[i]; mx = fmaxf(mx, w[i]); }
  float sum = 0.f;
#pragma unroll
  for (int i = 0; i < 12; ++i) { w[i] = __expf(w[i] - mx); sum += w[i]; }
  const float inv = 1.f / sum;
#pragma unroll
  for (int i = 0; i < 12; ++i) w[i] *= inv;

  const float* rp = refp + (size_t)bs * (kL * 2);
  const unsigned short* vbase = value + ((size_t)(b * kH + h) * kS) * kDh + lane * 8;

  const int LH[3] = {100, 50, 25}, LW[3] = {100, 50, 25}, LS[3] = {0, 10000, 12500};
  f32x2 acc[4] = {};
#pragma unroll
  for (int l = 0; l < 3; ++l) {
    const int Wi = LW[l], Hi = LH[l];
    const float Wl = (float)Wi, Hl = (float)Hi;
    const float rxw = rp[l * 2 + 0] * Wl - 0.5f;
    const float ryh = rp[l * 2 + 1] * Hl - 0.5f;
    const unsigned short* lvl = vbase + (size_t)LS[l] * kDh;
#pragma unroll
    for (int p = 0; p < 4; ++p) {
      const float ox = op[l * 8 + p * 2 + 0], oy = op[l * 8 + p * 2 + 1];
      const float xf = rxw + ox;
      const float yf = ryh + oy;
      const float x0f = floorf(xf), y0f = floorf(yf);
      const float fx = xf - x0f, fy = yf - y0f;
      const int x0 = (int)x0f, y0 = (int)y0f;
      const int x1 = x0 + 1, y1 = y0 + 1;
      const bool vx0 = (unsigned)x0 < (unsigned)Wi;
      const bool vx1 = (unsigned)x1 < (unsigned)Wi;
      const bool vy0 = (unsigned)y0 < (unsigned)Hi;
      const bool vy1 = (unsigned)y1 < (unsigned)Hi;
      const int cx0 = min(max(x0, 0), Wi - 1), cx1 = min(max(x1, 0), Wi - 1);
      const int cy0 = min(max(y0, 0), Hi - 1), cy1 = min(max(y1, 0), Hi - 1);
      const float aw = w[l * 4 + p];
      const float ax = aw * fx, a0 = aw - ax;
      const float w00 = a0 - a0 * fy, w10 = a0 * fy;
      const float w01 = ax - ax * fy, w11 = ax * fy;
      const float m00 = (vx0 && vy0) ? w00 : 0.f;
      const float m01 = (vx1 && vy0) ? w01 : 0.f;
      const float m10 = (vx0 && vy1) ? w10 : 0.f;
      const float m11 = (vx1 && vy1) ? w11 : 0.f;
      const int ry0 = cy0 * Wi, ry1 = cy1 * Wi;
      const uint4 q00 = *(const uint4*)(lvl + (size_t)(ry0 + cx0) * kDh);
      const uint4 q01 = *(const uint4*)(lvl + (size_t)(ry0 + cx1) * kDh);
      const uint4 q10 = *(const uint4*)(lvl + (size_t)(ry1 + cx0) * kDh);
      const uint4 q11 = *(const uint4*)(lvl + (size_t)(ry1 + cx1) * kDh);
      acc_corner(acc, q00, m00);
      acc_corner(acc, q01, m01);
      acc_corner(acc, q10, m10);
      acc_corner(acc, q11, m11);
    }
  }
  unsigned short r[8];
#pragma unroll
  for (int i = 0; i < 4; ++i) {
    r[2 * i] = f2bf(acc[i].x);
    r[2 * i + 1] = f2bf(acc[i].y);
  }
  *(short8v*)(out + (size_t)bs * kD + h * kDh + lane * 8) = *(const short8v*)r;
}

// ------------- fused residual + layernorm: out = LN(X + Ab) -----------------
template <int WB>
__global__ __launch_bounds__(256) void lnres_kernel(const float* __restrict__ X,
                                                    const unsigned short* __restrict__ Ab,
                                                    const float* __restrict__ g,
                                                    const float* __restrict__ be,
                                                    float* __restrict__ out,
                                                    unsigned short* __restrict__ outb,
                                                    int rows) {
  const int wid = threadIdx.x >> 6, lane = threadIdx.x & 63;
  const int row = blockIdx.x * 4 + wid;
  if (row >= rows) return;
  const float4 v = ((const float4*)(X + (size_t)row * kD))[lane];
  const ushort4 a4 = ((const ushort4*)(Ab + (size_t)row * kD))[lane];
  float4 t;
  t.x = v.x + bf2f(a4.x);
  t.y = v.y + bf2f(a4.y);
  t.z = v.z + bf2f(a4.z);
  t.w = v.w + bf2f(a4.w);
  float s = t.x + t.y + t.z + t.w;
  float sq = t.x * t.x + t.y * t.y + t.z * t.z + t.w * t.w;
#pragma unroll
  for (int o = 1; o < 64; o <<= 1) {
    s += __shfl_xor(s, o);
    sq += __shfl_xor(sq, o);
  }
  const float mean = s * (1.f / kD);
  const float var = sq * (1.f / kD) - mean * mean;
  const float rs = rsqrtf(var + 1e-5f);
  const float4 gg = ((const float4*)g)[lane];
  const float4 bb = ((const float4*)be)[lane];
  float4 o4;
  o4.x = (t.x - mean) * rs * gg.x + bb.x;
  o4.y = (t.y - mean) * rs * gg.y + bb.y;
  o4.z = (t.z - mean) * rs * gg.z + bb.z;
  o4.w = (t.w - mean) * rs * gg.w + bb.w;
  ((float4*)(out + (size_t)row * kD))[lane] = o4;
  if (WB) {
    ((ushort4*)(outb + (size_t)row * kD))[lane] =
        make_ushort4(f2bf(o4.x), f2bf(o4.y), f2bf(o4.z), f2bf(o4.w));
  }
}

}  // namespace

extern "C" void kernel_launch(void* const* d_in, const int* in_sizes, int n_in,
                              void* d_out, int out_size, void* d_ws, size_t ws_size,
                              hipStream_t stream) {
  const float* x      = (const float*)d_in[0];
  const float* pos    = (const float*)d_in[1];
  const float* refp   = (const float*)d_in[2];
  const float* W_off  = (const float*)d_in[3];
  const float* b_off  = (const float*)d_in[4];
  const float* W_attn = (const float*)d_in[5];
  const float* b_attn = (const float*)d_in[6];
  const float* W_val  = (const float*)d_in[7];
  const float* b_val  = (const float*)d_in[8];
  const float* W_out  = (const float*)d_in[9];
  const float* b_out  = (const float*)d_in[10];
  const float* g1     = (const float*)d_in[11];
  const float* be1    = (const float*)d_in[12];
  const float* W1     = (const float*)d_in[13];
  const float* b1     = (const float*)d_in[14];
  const float* W2     = (const float*)d_in[15];
  const float* b2     = (const float*)d_in[16];
  const float* g2     = (const float*)d_in[17];
  const float* be2    = (const float*)d_in[18];
  float* outp = (float*)d_out;

  // ---- workspace layout (bytes), peak ~139 MB.
  char* ws = (char*)d_ws;
  unsigned short* Wvt = (unsigned short*)(ws + 0);        // 256x256
  unsigned short* Wot = (unsigned short*)(ws + 131072);   // 256x256
  unsigned short* Wct = (unsigned short*)(ws + 262144);   // 384x256 (288 used)
  float* bcomb        = (float*)(ws + 262144 + 288 * 512);
  unsigned short* W1t = (unsigned short*)(ws + 458752);   // 1024x256
  unsigned short* W2t = (unsigned short*)(ws + 983040);   // 256x1024
  const size_t MDb = (size_t)kM * kD * 2;                 // 13,440,000 B
  char* regA = ws + 1507328;                 // xb -> aob
  char* regB = regA + MDb;                   // qb -> f2b
  char* regC = regB + MDb;                   // value+oa -> h1+h1b
  char* regG = regC + 43680000;              // sv (bf16)

  unsigned short* xb    = (unsigned short*)regA;
  unsigned short* aob   = (unsigned short*)regA;  // attn-out bf16 (xb dead)
  unsigned short* qb    = (unsigned short*)regB;
  unsigned short* f2b   = (unsigned short*)regB;  // ffn-out bf16 (qb dead)
  unsigned short* value = (unsigned short*)regC;  // head-major [B,H,S,Dh]
  float* oa   = (float*)(regC + MDb);             // [M][288]
  float* h1   = (float*)regC;                     // f32 (value+oa dead)
  unsigned short* h1b = (unsigned short*)(regC + (size_t)kM * kD * 4);
  unsigned short* sv  = (unsigned short*)regG;    // sampled attn (bf16)

  const dim3 blk(256);
  const int mt64 = (kM + 63) / 64;  // 411
  const int n4 = kM * kD / 4;

  // 0. all weight transpose+cast in ONE launch
  wprep_all<<<(729088 + 255) / 256, blk, 0, stream>>>(W_val, W_out, W_off, W_attn,
                                                      b_off, b_attn, W1, W2,
                                                      Wvt, Wot, Wct, bcomb, W1t, W2t);
  // 1. xb = bf16(x); qb = bf16(x + pos)
  prep_kernel<<<(n4 + 255) / 256, blk, 0, stream>>>((const float4*)x, (const float4*)pos,
                                                    (ushort4*)xb, (ushort4*)qb, n4);
  // 2+3. value AND oa in ONE launch
  qkvoa_gemm<<<dim3(5, mt64), blk, 0, stream>>>(xb, Wvt, b_val, value,
                                                qb, Wct, bcomb, oa, kM);
  // 4. softmax + deformable sampling -> sv (bf16)
  sample_kernel<<<(kB * kS * kH + 63) / 64, blk, 0, stream>>>(value, oa, refp, sv);
  // 5. aob = sv @ Wo + b_out (bf16; residual deferred to lnres)
  mfma_gemm<0, true, false><<<dim3(2, mt64), blk, 0, stream>>>(sv, Wot, b_out, aob,
                                                               kM, 256, 256);
  // 6. h1 = LN(x + aob) (f32 + bf16)
  lnres_kernel<1><<<(kM + 3) / 4, blk, 0, stream>>>(x, aob, g1, be1, h1, h1b, kM);
  // 7. f2b = relu(h1b @ W1 + b1) @ W2 + b2 (fused FFN v8, bf16)
  ffn_fused<<<mt64, blk, 0, stream>>>(h1b, W1t, W2t, b1, b2, f2b, kM);
  // 8. out = LN(h1 + f2b)
  lnres_kernel<0><<<(kM + 3) / 4, blk, 0, stream>>>(h1, f2b, g2, be2, outp, nullptr, kM);
}

// Round 15
// 190.965 us; speedup vs baseline: 1.1128x; 1.1128x over previous
//
#include <hip/hip_runtime.h>
#include <hip/hip_bf16.h>

namespace {

constexpr int kB = 2, kS = 13125, kD = 256, kH = 8, kL = 3, kP = 4, kFFN = 1024, kDh = 32;
constexpr int kM = kB * kS;  // 26250

typedef __attribute__((ext_vector_type(8))) short short8v;
typedef __attribute__((ext_vector_type(4))) float f32x4;
typedef __attribute__((ext_vector_type(2))) float f32x2;
typedef __attribute__((ext_vector_type(2))) unsigned int uint2v;

__device__ __forceinline__ float bf2f(unsigned short u) {
  unsigned int x = ((unsigned int)u) << 16;
  return __builtin_bit_cast(float, x);
}
__device__ __forceinline__ unsigned short f2bf(float f) {
  unsigned int u = __builtin_bit_cast(unsigned int, f);
  u += 0x7FFFu + ((u >> 16) & 1u);  // RNE
  return (unsigned short)(u >> 16);
}

__device__ __forceinline__ void gload_lds16(const void* g, void* l) {
  __builtin_amdgcn_global_load_lds(
      (const __attribute__((address_space(1))) unsigned int*)g,
      (__attribute__((address_space(3))) unsigned int*)l, 16, 0, 0);
}

// ---------------- merged weight prep (one launch for all 5 matrices) --------
__global__ __launch_bounds__(256) void wprep_all(const float* __restrict__ Wv,
                                                 const float* __restrict__ Wo,
                                                 const float* __restrict__ Woff,
                                                 const float* __restrict__ Wattn,
                                                 const float* __restrict__ boff,
                                                 const float* __restrict__ battn,
                                                 const float* __restrict__ W1,
                                                 const float* __restrict__ W2,
                                                 unsigned short* __restrict__ Wvt,
                                                 unsigned short* __restrict__ Wot,
                                                 unsigned short* __restrict__ Wct,
                                                 float* __restrict__ bcomb,
                                                 unsigned short* __restrict__ W1t,
                                                 unsigned short* __restrict__ W2t) {
  int idx = blockIdx.x * 256 + threadIdx.x;
  if (idx < 65536) {                       // Wvt: [256n][256k]
    int n = idx >> 8, k = idx & 255;
    Wvt[idx] = f2bf(Wv[k * 256 + n]);
  } else if (idx < 131072) {               // Wot
    int j = idx - 65536;
    int n = j >> 8, k = j & 255;
    Wot[j] = f2bf(Wo[k * 256 + n]);
  } else if (idx < 204800) {               // Wct: 288 x 256, per-head interleave
    int j = idx - 131072;
    int n = j >> 8, k = j & 255;
    int h = n / 36, jj = n - h * 36;
    float v = (jj < 24) ? Woff[(size_t)k * 192 + h * 24 + jj]
                        : Wattn[(size_t)k * 96 + h * 12 + (jj - 24)];
    Wct[j] = f2bf(v);
    if (j < 288) {
      int hh = j / 36, q = j - hh * 36;
      bcomb[j] = (q < 24) ? boff[hh * 24 + q] : battn[hh * 12 + (q - 24)];
    }
  } else if (idx < 466944) {               // W1t: 1024 x 256
    int j = idx - 204800;
    int n = j >> 8, k = j & 255;
    W1t[j] = f2bf(W1[(size_t)k * 1024 + n]);
  } else if (idx < 729088) {               // W2t: 256 x 1024 (K=1024)
    int j = idx - 466944;
    int n = j >> 10, k = j & 1023;
    W2t[j] = f2bf(W2[(size_t)k * 256 + n]);
  }
}

// ---------------- xb = bf16(x); qb = bf16(x + pos)  (x read once) ----------
__global__ __launch_bounds__(256) void prep_kernel(const float4* __restrict__ x,
                                                   const float4* __restrict__ pos,
                                                   ushort4* __restrict__ xb,
                                                   ushort4* __restrict__ qb, int n4) {
  int i = blockIdx.x * 256 + threadIdx.x;
  if (i < n4) {
    float4 a = x[i], b = pos[i];
    xb[i] = make_ushort4(f2bf(a.x), f2bf(a.y), f2bf(a.z), f2bf(a.w));
    qb[i] = make_ushort4(f2bf(a.x + b.x), f2bf(a.y + b.y),
                         f2bf(a.z + b.z), f2bf(a.w + b.w));
  }
}

// ---------------- bf16 MFMA GEMM body (device fn, proven structure) ---------
template <int EPI, bool OBF, bool VHM>
__device__ __forceinline__ void gemm_body(const unsigned short* __restrict__ A,
                                          const unsigned short* __restrict__ Bt,
                                          const float* __restrict__ bias,
                                          void* __restrict__ Cp,
                                          int M, int N, int K, int bx, int by,
                                          unsigned short* smem) {
  constexpr int MI = 2;
  constexpr int BM = 64;
  unsigned short* As = smem;
  unsigned short* Bs = smem + BM * 32;
  const int tid = threadIdx.x;
  const int w = tid >> 6, lane = tid & 63;
  const int m0 = by * BM, n0 = bx * 128;
  const int wr = w >> 1, wc = w & 1;
  const int r_ = lane >> 2, sl = lane & 3;

  f32x4 acc[MI][4] = {};

  for (int k0 = 0; k0 < K; k0 += 32) {
    {
      const int row = w * 16 + r_;
      const int sg = sl ^ ((row >> 1) & 3);
      int arow = m0 + row;
      arow = arow < M ? arow : M - 1;
      gload_lds16(A + (size_t)arow * K + k0 + sg * 8, &As[(w * 16) * 32]);
    }
#pragma unroll
    for (int i = 0; i < 2; ++i) {
      const int row = i * 64 + w * 16 + r_;
      const int sg = sl ^ ((row >> 1) & 3);
      gload_lds16(Bt + (size_t)(n0 + row) * K + k0 + sg * 8, &Bs[(i * 64 + w * 16) * 32]);
    }
    __syncthreads();
    short8v a[MI], b[4];
#pragma unroll
    for (int mi = 0; mi < MI; ++mi) {
      const int row = wr * (MI * 16) + mi * 16 + (lane & 15);
      const int slot = (lane >> 4) ^ ((row >> 1) & 3);
      a[mi] = *(const short8v*)&As[row * 32 + slot * 8];
    }
#pragma unroll
    for (int ni = 0; ni < 4; ++ni) {
      const int row = wc * 64 + ni * 16 + (lane & 15);
      const int slot = (lane >> 4) ^ ((row >> 1) & 3);
      b[ni] = *(const short8v*)&Bs[row * 32 + slot * 8];
    }
#pragma unroll
    for (int mi = 0; mi < MI; ++mi)
#pragma unroll
      for (int ni = 0; ni < 4; ++ni)
        acc[mi][ni] = __builtin_amdgcn_mfma_f32_16x16x32_bf16(a[mi], b[ni], acc[mi][ni], 0, 0, 0);
    __syncthreads();
  }

  const int cr = lane >> 4, cc = lane & 15;
  if (OBF) {
    unsigned short* Cs = smem;  // 64 rows x 128 cols, chunk-XOR swizzled
#pragma unroll
    for (int ni = 0; ni < 4; ++ni) {
      const int col = wc * 64 + ni * 16 + cc;
      const float bv = bias[n0 + col];
#pragma unroll
      for (int mi = 0; mi < MI; ++mi)
#pragma unroll
        for (int r = 0; r < 4; ++r) {
          const int loc = wr * (MI * 16) + mi * 16 + cr * 4 + r;
          float v = acc[mi][ni][r] + bv;
          if (EPI == 2) v = fmaxf(v, 0.f);
          const int ch = (col >> 3) ^ (loc & 7);
          Cs[loc * 128 + ch * 8 + (col & 7)] = f2bf(v);
        }
    }
    __syncthreads();
    const int lr = tid >> 4, lc = tid & 15;
#pragma unroll
    for (int pp = 0; pp < 4; ++pp) {
      const int loc = pp * 16 + lr;
      const int grow = m0 + loc;
      const short8v vv = *(const short8v*)&Cs[loc * 128 + ((lc ^ (loc & 7)) * 8)];
      if (grow < M) {
        if (VHM) {
          const int col = n0 + lc * 8;
          const int bb = grow >= kS ? 1 : 0;
          const int ss = grow - bb * kS;
          const int hh = col >> 5;
          *(short8v*)((unsigned short*)Cp +
                      (((size_t)(bb * kH + hh) * kS + ss) * kDh + (col & 31))) = vv;
        } else {
          *(short8v*)((unsigned short*)Cp + (size_t)grow * N + n0 + lc * 8) = vv;
        }
      }
    }
    __syncthreads();
  } else {
#pragma unroll
    for (int ni = 0; ni < 4; ++ni) {
      const int col = n0 + wc * 64 + ni * 16 + cc;
      if (col >= N) continue;
      const float bv = bias[col];
#pragma unroll
      for (int mi = 0; mi < MI; ++mi) {
#pragma unroll
        for (int r = 0; r < 4; ++r) {
          const int row = m0 + wr * (MI * 16) + mi * 16 + cr * 4 + r;
          if (row >= M) continue;
          ((float*)Cp)[(size_t)row * N + col] = acc[mi][ni][r] + bv;
        }
      }
    }
  }
}

// generic single-GEMM wrapper (used for aob)
template <int EPI, bool OBF, bool VHM>
__global__ __launch_bounds__(256) void mfma_gemm(const unsigned short* __restrict__ A,
                                                 const unsigned short* __restrict__ Bt,
                                                 const float* __restrict__ bias,
                                                 void* __restrict__ Cp,
                                                 int M, int N, int K) {
  __shared__ unsigned short smem[2 * 128 * 32];
  gemm_body<EPI, OBF, VHM>(A, Bt, bias, Cp, M, N, K, blockIdx.x, blockIdx.y, smem);
}

// merged value+oa GEMM: grid (5, mt64). bx<2 -> value (bf16 head-major),
// bx>=2 -> oa (f32). Block-uniform branch; doubles resident blocks/CU for
// this phase and removes one launch gap.
__global__ __launch_bounds__(256) void qkvoa_gemm(const unsigned short* __restrict__ xb,
                                                  const unsigned short* __restrict__ Wvt,
                                                  const float* __restrict__ bval,
                                                  unsigned short* __restrict__ value,
                                                  const unsigned short* __restrict__ qb,
                                                  const unsigned short* __restrict__ Wct,
                                                  const float* __restrict__ bcomb,
                                                  float* __restrict__ oa,
                                                  int M) {
  __shared__ unsigned short smem[2 * 128 * 32];
  if (blockIdx.x < 2) {
    gemm_body<0, true, true>(xb, Wvt, bval, value, M, 256, 256, blockIdx.x, blockIdx.y, smem);
  } else {
    gemm_body<0, false, false>(qb, Wct, bcomb, oa, M, 288, 256, blockIdx.x - 2, blockIdx.y, smem);
  }
}

// ---------------- fused FFN v4 (PROVEN BEST, 59.3 us) -----------------------
// out = relu(A @ W1 + b1) @ W2 + b2 (bf16). 64-row block, 4 waves.
// W1 double-buffered in LDS via global_load_lds (conflict-free [kk][64][32]
// slot-XOR layout), A-fragments in registers, P through 8 KB swizzled LDS,
// two barriers per jt; W2 fragments hoisted to registers pre-stage-1.
__global__ __launch_bounds__(256) void ffn_fused(const unsigned short* __restrict__ Ain,
                                                 const unsigned short* __restrict__ W1t,
                                                 const unsigned short* __restrict__ W2t,
                                                 const float* __restrict__ b1,
                                                 const float* __restrict__ b2,
                                                 unsigned short* __restrict__ Cp,
                                                 int M) {
  __shared__ unsigned short W1s[2][64 * 256];  // 2 x 32 KB, [kk][row][32] swizzled
  __shared__ unsigned short Ps[2 * 64 * 32];   // 8 KB, [kb][row(m)][32] swizzled
  const int tid = threadIdx.x;
  const int w = tid >> 6, lane = tid & 63;
  const int m0 = blockIdx.x * 64;
  const int cr = lane >> 4, cc = lane & 15;

  short8v areg[8];
  {
    int grow = m0 + w * 16 + cc;
    grow = grow < M ? grow : M - 1;
    const unsigned short* ap = Ain + (size_t)grow * 256 + cr * 8;
#pragma unroll
    for (int kk = 0; kk < 8; ++kk) areg[kk] = *(const short8v*)(ap + kk * 32);
  }

  auto stage_w1 = [&](int jt, int buf) {
    const unsigned short* src = W1t + (size_t)jt * 64 * 256;
#pragma unroll
    for (int it = 0; it < 8; ++it) {
      const int idx = it * 256 + tid;      // 16B-chunk id, 0..2047
      const int kk = idx >> 8;
      const int row = (idx >> 2) & 63;
      const int sl = idx & 3;
      const int ssl = sl ^ ((row >> 1) & 3);
      gload_lds16(src + (size_t)row * 256 + kk * 32 + ssl * 8, &W1s[buf][idx * 8]);
    }
  };

  f32x4 acc[4][4] = {};  // [mi][ni]: rows mi*16+cr*4+r, cols w*64+ni*16+cc

  stage_w1(0, 0);
  __syncthreads();  // W1s[0] ready

  for (int jt = 0; jt < 16; ++jt) {
    const int buf = jt & 1;
    if (jt < 15) stage_w1(jt + 1, buf ^ 1);  // async prefetch, overlaps stage 1

    // hoist this jt's W2 fragments into registers (independent of LDS)
    short8v w2f[8];
#pragma unroll
    for (int kk2 = 0; kk2 < 2; ++kk2)
#pragma unroll
      for (int ni = 0; ni < 4; ++ni)
        w2f[kk2 * 4 + ni] = *(const short8v*)(W2t +
            (size_t)(w * 64 + ni * 16 + cc) * 1024 + jt * 64 + kk2 * 32 + cr * 8);

    // ---- stage 1: p1[ni] = sum_kk mfma(w1frag, areg)  (reg = ffn, cc = m)
    f32x4 p1[4] = {};
#pragma unroll
    for (int kk = 0; kk < 8; ++kk) {
#pragma unroll
      for (int ni = 0; ni < 4; ++ni) {
        const int row = ni * 16 + cc;
        const short8v wv = *(const short8v*)
            &W1s[buf][kk * 2048 + row * 32 + ((cr ^ ((row >> 1) & 3)) * 8)];
        p1[ni] = __builtin_amdgcn_mfma_f32_16x16x32_bf16(wv, areg[kk], p1[ni], 0, 0, 0);
      }
    }
    // bias + relu + bf16-pack; lane holds P[m=w*16+cc][ffn=ni*16+cr*4+r]
    {
      const int row = w * 16 + cc;
      const int rsw = (row >> 1) & 3;
#pragma unroll
      for (int ni = 0; ni < 4; ++ni) {
        const float4 bv = *(const float4*)&b1[jt * 64 + ni * 16 + cr * 4];
        const unsigned int u0 =
            (unsigned)f2bf(fmaxf(p1[ni][0] + bv.x, 0.f)) |
            ((unsigned)f2bf(fmaxf(p1[ni][1] + bv.y, 0.f)) << 16);
        const unsigned int u1 =
            (unsigned)f2bf(fmaxf(p1[ni][2] + bv.z, 0.f)) |
            ((unsigned)f2bf(fmaxf(p1[ni][3] + bv.w, 0.f)) << 16);
        const int kb = ni >> 1;
        const int slot = (ni & 1) * 2 + (cr >> 1);
        uint2v* dst = (uint2v*)&Ps[kb * 2048 + row * 32 + ((slot ^ rsw) * 8) + (cr & 1) * 4];
        *dst = (uint2v){u0, u1};
      }
    }
    __syncthreads();  // Ps visible; drains W1 prefetch (overlapped stage 1)

    // ---- stage 2: acc += P @ W2 (W2 frags already in registers)
#pragma unroll
    for (int kk2 = 0; kk2 < 2; ++kk2) {
      short8v pf[4];
#pragma unroll
      for (int mi = 0; mi < 4; ++mi) {
        const int row = mi * 16 + cc;
        pf[mi] = *(const short8v*)
            &Ps[kk2 * 2048 + row * 32 + ((cr ^ ((row >> 1) & 3)) * 8)];
      }
#pragma unroll
      for (int ni = 0; ni < 4; ++ni) {
#pragma unroll
        for (int mi = 0; mi < 4; ++mi)
          acc[mi][ni] = __builtin_amdgcn_mfma_f32_16x16x32_bf16(pf[mi], w2f[kk2 * 4 + ni],
                                                               acc[mi][ni], 0, 0, 0);
      }
    }
    __syncthreads();  // Ps reads done before next jt's writes
  }

  // epilogue: stage bf16 C tile into W1s[0] (reuse), then full-line stores
  unsigned short* Cs = &W1s[0][0];
#pragma unroll
  for (int ni = 0; ni < 4; ++ni) {
    const int col = w * 64 + ni * 16 + cc;
    const float bv = b2[col];
#pragma unroll
    for (int mi = 0; mi < 4; ++mi)
#pragma unroll
      for (int r = 0; r < 4; ++r) {
        const int row = mi * 16 + cr * 4 + r;
        const float v = acc[mi][ni][r] + bv;
        Cs[row * 256 + (((col >> 3) ^ (row & 7)) * 8) + (col & 7)] = f2bf(v);
      }
  }
  __syncthreads();
#pragma unroll
  for (int it = 0; it < 8; ++it) {
    const int row = it * 8 + (tid >> 5);
    const int grow = m0 + row;
    const int ch = tid & 31;
    const short8v vv = *(const short8v*)&Cs[row * 256 + ((ch ^ (row & 7)) * 8)];
    if (grow < M) *(short8v*)(Cp + (size_t)grow * 256 + ch * 8) = vv;
  }
}

// ---------------- deformable sampling (value head-major bf16 -> sv bf16) ----
__device__ __forceinline__ void acc2u(f32x2* acc, unsigned u, int i, float m) {
  f32x2 v;
  v.x = __builtin_bit_cast(float, u << 16);
  v.y = __builtin_bit_cast(float, u & 0xFFFF0000u);
  acc[i] += m * v;
}
__device__ __forceinline__ void acc_corner(f32x2* acc, uint4 q, float m) {
  acc2u(acc, q.x, 0, m);
  acc2u(acc, q.y, 1, m);
  acc2u(acc, q.z, 2, m);
  acc2u(acc, q.w, 3, m);
}

__global__ __launch_bounds__(256) void sample_kernel(const unsigned short* __restrict__ value,
                                                     const float* __restrict__ oa,
                                                     const float* __restrict__ refp,
                                                     unsigned short* __restrict__ out) {
  const int tid = threadIdx.x;
  const int sub = tid >> 2;    // 64 queries per block
  const int lane = tid & 3;    // 4 lanes x 8 channels
  const int gi = blockIdx.x * 64 + sub;  // index over B*S*H
  if (gi >= kB * kS * kH) return;
  const int h = gi & 7;
  const int bs = gi >> 3;
  const int b = (bs >= kS) ? 1 : 0;  // kB == 2

  const float* op = oa + (size_t)bs * 288 + h * 36;
  const float* al = op + 24;
  float w[12];
  float mx = -1e30f;
#pragma unroll
  for (int i = 0; i < 12; ++i) { w[i] = al[i]; mx = fmaxf(mx, w[i]); }
  float sum = 0.f;
#pragma unroll
  for (int i = 0; i < 12; ++i) { w[i] = __expf(w[i] - mx); sum += w[i]; }
  const float inv = 1.f / sum;
#pragma unroll
  for (int i = 0; i < 12; ++i) w[i] *= inv;

  const float* rp = refp + (size_t)bs * (kL * 2);
  const unsigned short* vbase = value + ((size_t)(b * kH + h) * kS) * kDh + lane * 8;

  const int LH[3] = {100, 50, 25}, LW[3] = {100, 50, 25}, LS[3] = {0, 10000, 12500};
  f32x2 acc[4] = {};
#pragma unroll
  for (int l = 0; l < 3; ++l) {
    const int Wi = LW[l], Hi = LH[l];
    const float Wl = (float)Wi, Hl = (float)Hi;
    const float rxw = rp[l * 2 + 0] * Wl - 0.5f;
    const float ryh = rp[l * 2 + 1] * Hl - 0.5f;
    const unsigned short* lvl = vbase + (size_t)LS[l] * kDh;
#pragma unroll
    for (int p = 0; p < 4; ++p) {
      const float ox = op[l * 8 + p * 2 + 0], oy = op[l * 8 + p * 2 + 1];
      const float xf = rxw + ox;
      const float yf = ryh + oy;
      const float x0f = floorf(xf), y0f = floorf(yf);
      const float fx = xf - x0f, fy = yf - y0f;
      const int x0 = (int)x0f, y0 = (int)y0f;
      const int x1 = x0 + 1, y1 = y0 + 1;
      const bool vx0 = (unsigned)x0 < (unsigned)Wi;
      const bool vx1 = (unsigned)x1 < (unsigned)Wi;
      const bool vy0 = (unsigned)y0 < (unsigned)Hi;
      const bool vy1 = (unsigned)y1 < (unsigned)Hi;
      const int cx0 = min(max(x0, 0), Wi - 1), cx1 = min(max(x1, 0), Wi - 1);
      const int cy0 = min(max(y0, 0), Hi - 1), cy1 = min(max(y1, 0), Hi - 1);
      const float aw = w[l * 4 + p];
      const float ax = aw * fx, a0 = aw - ax;
      const float w00 = a0 - a0 * fy, w10 = a0 * fy;
      const float w01 = ax - ax * fy, w11 = ax * fy;
      const float m00 = (vx0 && vy0) ? w00 : 0.f;
      const float m01 = (vx1 && vy0) ? w01 : 0.f;
      const float m10 = (vx0 && vy1) ? w10 : 0.f;
      const float m11 = (vx1 && vy1) ? w11 : 0.f;
      const int ry0 = cy0 * Wi, ry1 = cy1 * Wi;
      const uint4 q00 = *(const uint4*)(lvl + (size_t)(ry0 + cx0) * kDh);
      const uint4 q01 = *(const uint4*)(lvl + (size_t)(ry0 + cx1) * kDh);
      const uint4 q10 = *(const uint4*)(lvl + (size_t)(ry1 + cx0) * kDh);
      const uint4 q11 = *(const uint4*)(lvl + (size_t)(ry1 + cx1) * kDh);
      acc_corner(acc, q00, m00);
      acc_corner(acc, q01, m01);
      acc_corner(acc, q10, m10);
      acc_corner(acc, q11, m11);
    }
  }
  unsigned short r[8];
#pragma unroll
  for (int i = 0; i < 4; ++i) {
    r[2 * i] = f2bf(acc[i].x);
    r[2 * i + 1] = f2bf(acc[i].y);
  }
  *(short8v*)(out + (size_t)bs * kD + h * kDh + lane * 8) = *(const short8v*)r;
}

// ------------- fused residual + layernorm: out = LN(X + Ab) -----------------
template <int WB>
__global__ __launch_bounds__(256) void lnres_kernel(const float* __restrict__ X,
                                                    const unsigned short* __restrict__ Ab,
                                                    const float* __restrict__ g,
                                                    const float* __restrict__ be,
                                                    float* __restrict__ out,
                                                    unsigned short* __restrict__ outb,
                                                    int rows) {
  const int wid = threadIdx.x >> 6, lane = threadIdx.x & 63;
  const int row = blockIdx.x * 4 + wid;
  if (row >= rows) return;
  const float4 v = ((const float4*)(X + (size_t)row * kD))[lane];
  const ushort4 a4 = ((const ushort4*)(Ab + (size_t)row * kD))[lane];
  float4 t;
  t.x = v.x + bf2f(a4.x);
  t.y = v.y + bf2f(a4.y);
  t.z = v.z + bf2f(a4.z);
  t.w = v.w + bf2f(a4.w);
  float s = t.x + t.y + t.z + t.w;
  float sq = t.x * t.x + t.y * t.y + t.z * t.z + t.w * t.w;
#pragma unroll
  for (int o = 1; o < 64; o <<= 1) {
    s += __shfl_xor(s, o);
    sq += __shfl_xor(sq, o);
  }
  const float mean = s * (1.f / kD);
  const float var = sq * (1.f / kD) - mean * mean;
  const float rs = rsqrtf(var + 1e-5f);
  const float4 gg = ((const float4*)g)[lane];
  const float4 bb = ((const float4*)be)[lane];
  float4 o4;
  o4.x = (t.x - mean) * rs * gg.x + bb.x;
  o4.y = (t.y - mean) * rs * gg.y + bb.y;
  o4.z = (t.z - mean) * rs * gg.z + bb.z;
  o4.w = (t.w - mean) * rs * gg.w + bb.w;
  ((float4*)(out + (size_t)row * kD))[lane] = o4;
  if (WB) {
    ((ushort4*)(outb + (size_t)row * kD))[lane] =
        make_ushort4(f2bf(o4.x), f2bf(o4.y), f2bf(o4.z), f2bf(o4.w));
  }
}

}  // namespace

extern "C" void kernel_launch(void* const* d_in, const int* in_sizes, int n_in,
                              void* d_out, int out_size, void* d_ws, size_t ws_size,
                              hipStream_t stream) {
  const float* x      = (const float*)d_in[0];
  const float* pos    = (const float*)d_in[1];
  const float* refp   = (const float*)d_in[2];
  const float* W_off  = (const float*)d_in[3];
  const float* b_off  = (const float*)d_in[4];
  const float* W_attn = (const float*)d_in[5];
  const float* b_attn = (const float*)d_in[6];
  const float* W_val  = (const float*)d_in[7];
  const float* b_val  = (const float*)d_in[8];
  const float* W_out  = (const float*)d_in[9];
  const float* b_out  = (const float*)d_in[10];
  const float* g1     = (const float*)d_in[11];
  const float* be1    = (const float*)d_in[12];
  const float* W1     = (const float*)d_in[13];
  const float* b1     = (const float*)d_in[14];
  const float* W2     = (const float*)d_in[15];
  const float* b2     = (const float*)d_in[16];
  const float* g2     = (const float*)d_in[17];
  const float* be2    = (const float*)d_in[18];
  float* outp = (float*)d_out;

  // ---- workspace layout (bytes), peak ~139 MB.
  char* ws = (char*)d_ws;
  unsigned short* Wvt = (unsigned short*)(ws + 0);        // 256x256
  unsigned short* Wot = (unsigned short*)(ws + 131072);   // 256x256
  unsigned short* Wct = (unsigned short*)(ws + 262144);   // 384x256 (288 used)
  float* bcomb        = (float*)(ws + 262144 + 288 * 512);
  unsigned short* W1t = (unsigned short*)(ws + 458752);   // 1024x256
  unsigned short* W2t = (unsigned short*)(ws + 983040);   // 256x1024
  const size_t MDb = (size_t)kM * kD * 2;                 // 13,440,000 B
  char* regA = ws + 1507328;                 // xb -> aob
  char* regB = regA + MDb;                   // qb -> f2b
  char* regC = regB + MDb;                   // value+oa -> h1+h1b
  char* regG = regC + 43680000;              // sv (bf16)

  unsigned short* xb    = (unsigned short*)regA;
  unsigned short* aob   = (unsigned short*)regA;  // attn-out bf16 (xb dead)
  unsigned short* qb    = (unsigned short*)regB;
  unsigned short* f2b   = (unsigned short*)regB;  // ffn-out bf16 (qb dead)
  unsigned short* value = (unsigned short*)regC;  // head-major [B,H,S,Dh]
  float* oa   = (float*)(regC + MDb);             // [M][288]
  float* h1   = (float*)regC;                     // f32 (value+oa dead)
  unsigned short* h1b = (unsigned short*)(regC + (size_t)kM * kD * 4);
  unsigned short* sv  = (unsigned short*)regG;    // sampled attn (bf16)

  const dim3 blk(256);
  const int mt64 = (kM + 63) / 64;  // 411
  const int n4 = kM * kD / 4;

  // 0. all weight transpose+cast in ONE launch
  wprep_all<<<(729088 + 255) / 256, blk, 0, stream>>>(W_val, W_out, W_off, W_attn,
                                                      b_off, b_attn, W1, W2,
                                                      Wvt, Wot, Wct, bcomb, W1t, W2t);
  // 1. xb = bf16(x); qb = bf16(x + pos)
  prep_kernel<<<(n4 + 255) / 256, blk, 0, stream>>>((const float4*)x, (const float4*)pos,
                                                    (ushort4*)xb, (ushort4*)qb, n4);
  // 2+3. value AND oa in ONE launch (grid 5 x 411)
  qkvoa_gemm<<<dim3(5, mt64), blk, 0, stream>>>(xb, Wvt, b_val, value,
                                                qb, Wct, bcomb, oa, kM);
  // 4. softmax + deformable sampling -> sv (bf16)
  sample_kernel<<<(kB * kS * kH + 63) / 64, blk, 0, stream>>>(value, oa, refp, sv);
  // 5. aob = sv @ Wo + b_out (bf16; residual deferred to lnres)
  mfma_gemm<0, true, false><<<dim3(2, mt64), blk, 0, stream>>>(sv, Wot, b_out, aob,
                                                               kM, 256, 256);
  // 6. h1 = LN(x + aob) (f32 + bf16)
  lnres_kernel<1><<<(kM + 3) / 4, blk, 0, stream>>>(x, aob, g1, be1, h1, h1b, kM);
  // 7. f2b = relu(h1b @ W1 + b1) @ W2 + b2 (fused FFN v4, bf16)
  ffn_fused<<<mt64, blk, 0, stream>>>(h1b, W1t, W2t, b1, b2, f2b, kM);
  // 8. out = LN(h1 + f2b)
  lnres_kernel<0><<<(kM + 3) / 4, blk, 0, stream>>>(h1, f2b, g2, be2, outp, nullptr, kM);
}

// Round 16
// 182.891 us; speedup vs baseline: 1.1619x; 1.0441x over previous
//
#include <hip/hip_runtime.h>
#include <hip/hip_bf16.h>

namespace {

constexpr int kB = 2, kS = 13125, kD = 256, kH = 8, kL = 3, kP = 4, kFFN = 1024, kDh = 32;
constexpr int kM = kB * kS;  // 26250

typedef __attribute__((ext_vector_type(8))) short short8v;
typedef __attribute__((ext_vector_type(4))) float f32x4;
typedef __attribute__((ext_vector_type(2))) float f32x2;
typedef __attribute__((ext_vector_type(2))) unsigned int uint2v;

__device__ __forceinline__ float bf2f(unsigned short u) {
  unsigned int x = ((unsigned int)u) << 16;
  return __builtin_bit_cast(float, x);
}
__device__ __forceinline__ unsigned short f2bf(float f) {
  unsigned int u = __builtin_bit_cast(unsigned int, f);
  u += 0x7FFFu + ((u >> 16) & 1u);  // RNE
  return (unsigned short)(u >> 16);
}

__device__ __forceinline__ void gload_lds16(const void* g, void* l) {
  __builtin_amdgcn_global_load_lds(
      (const __attribute__((address_space(1))) unsigned int*)g,
      (__attribute__((address_space(3))) unsigned int*)l, 16, 0, 0);
}

// ---------------- merged weight prep (one launch for all 5 matrices) --------
__global__ __launch_bounds__(256) void wprep_all(const float* __restrict__ Wv,
                                                 const float* __restrict__ Wo,
                                                 const float* __restrict__ Woff,
                                                 const float* __restrict__ Wattn,
                                                 const float* __restrict__ boff,
                                                 const float* __restrict__ battn,
                                                 const float* __restrict__ W1,
                                                 const float* __restrict__ W2,
                                                 unsigned short* __restrict__ Wvt,
                                                 unsigned short* __restrict__ Wot,
                                                 unsigned short* __restrict__ Wct,
                                                 float* __restrict__ bcomb,
                                                 unsigned short* __restrict__ W1t,
                                                 unsigned short* __restrict__ W2t) {
  int idx = blockIdx.x * 256 + threadIdx.x;
  if (idx < 65536) {                       // Wvt: [256n][256k]
    int n = idx >> 8, k = idx & 255;
    Wvt[idx] = f2bf(Wv[k * 256 + n]);
  } else if (idx < 131072) {               // Wot
    int j = idx - 65536;
    int n = j >> 8, k = j & 255;
    Wot[j] = f2bf(Wo[k * 256 + n]);
  } else if (idx < 204800) {               // Wct: 288 x 256, per-head interleave
    int j = idx - 131072;
    int n = j >> 8, k = j & 255;
    int h = n / 36, jj = n - h * 36;
    float v = (jj < 24) ? Woff[(size_t)k * 192 + h * 24 + jj]
                        : Wattn[(size_t)k * 96 + h * 12 + (jj - 24)];
    Wct[j] = f2bf(v);
    if (j < 288) {
      int hh = j / 36, q = j - hh * 36;
      bcomb[j] = (q < 24) ? boff[hh * 24 + q] : battn[hh * 12 + (q - 24)];
    }
  } else if (idx < 466944) {               // W1t: 1024 x 256
    int j = idx - 204800;
    int n = j >> 8, k = j & 255;
    W1t[j] = f2bf(W1[(size_t)k * 1024 + n]);
  } else if (idx < 729088) {               // W2t: 256 x 1024 (K=1024)
    int j = idx - 466944;
    int n = j >> 10, k = j & 1023;
    W2t[j] = f2bf(W2[(size_t)k * 256 + n]);
  }
}

// ---------------- xb = bf16(x); qb = bf16(x + pos)  (x read once) ----------
__global__ __launch_bounds__(256) void prep_kernel(const float4* __restrict__ x,
                                                   const float4* __restrict__ pos,
                                                   ushort4* __restrict__ xb,
                                                   ushort4* __restrict__ qb, int n4) {
  int i = blockIdx.x * 256 + threadIdx.x;
  if (i < n4) {
    float4 a = x[i], b = pos[i];
    xb[i] = make_ushort4(f2bf(a.x), f2bf(a.y), f2bf(a.z), f2bf(a.w));
    qb[i] = make_ushort4(f2bf(a.x + b.x), f2bf(a.y + b.y),
                         f2bf(a.z + b.z), f2bf(a.w + b.w));
  }
}

// ---------------- bf16 MFMA GEMM body (device fn, proven structure) ---------
template <int EPI, bool OBF, bool VHM>
__device__ __forceinline__ void gemm_body(const unsigned short* __restrict__ A,
                                          const unsigned short* __restrict__ Bt,
                                          const float* __restrict__ bias,
                                          void* __restrict__ Cp,
                                          int M, int N, int K, int bx, int by,
                                          unsigned short* smem) {
  constexpr int MI = 2;
  constexpr int BM = 64;
  unsigned short* As = smem;
  unsigned short* Bs = smem + BM * 32;
  const int tid = threadIdx.x;
  const int w = tid >> 6, lane = tid & 63;
  const int m0 = by * BM, n0 = bx * 128;
  const int wr = w >> 1, wc = w & 1;
  const int r_ = lane >> 2, sl = lane & 3;

  f32x4 acc[MI][4] = {};

  for (int k0 = 0; k0 < K; k0 += 32) {
    {
      const int row = w * 16 + r_;
      const int sg = sl ^ ((row >> 1) & 3);
      int arow = m0 + row;
      arow = arow < M ? arow : M - 1;
      gload_lds16(A + (size_t)arow * K + k0 + sg * 8, &As[(w * 16) * 32]);
    }
#pragma unroll
    for (int i = 0; i < 2; ++i) {
      const int row = i * 64 + w * 16 + r_;
      const int sg = sl ^ ((row >> 1) & 3);
      gload_lds16(Bt + (size_t)(n0 + row) * K + k0 + sg * 8, &Bs[(i * 64 + w * 16) * 32]);
    }
    __syncthreads();
    short8v a[MI], b[4];
#pragma unroll
    for (int mi = 0; mi < MI; ++mi) {
      const int row = wr * (MI * 16) + mi * 16 + (lane & 15);
      const int slot = (lane >> 4) ^ ((row >> 1) & 3);
      a[mi] = *(const short8v*)&As[row * 32 + slot * 8];
    }
#pragma unroll
    for (int ni = 0; ni < 4; ++ni) {
      const int row = wc * 64 + ni * 16 + (lane & 15);
      const int slot = (lane >> 4) ^ ((row >> 1) & 3);
      b[ni] = *(const short8v*)&Bs[row * 32 + slot * 8];
    }
#pragma unroll
    for (int mi = 0; mi < MI; ++mi)
#pragma unroll
      for (int ni = 0; ni < 4; ++ni)
        acc[mi][ni] = __builtin_amdgcn_mfma_f32_16x16x32_bf16(a[mi], b[ni], acc[mi][ni], 0, 0, 0);
    __syncthreads();
  }

  const int cr = lane >> 4, cc = lane & 15;
  if (OBF) {
    unsigned short* Cs = smem;  // 64 rows x 128 cols, chunk-XOR swizzled
#pragma unroll
    for (int ni = 0; ni < 4; ++ni) {
      const int col = wc * 64 + ni * 16 + cc;
      const float bv = bias[n0 + col];
#pragma unroll
      for (int mi = 0; mi < MI; ++mi)
#pragma unroll
        for (int r = 0; r < 4; ++r) {
          const int loc = wr * (MI * 16) + mi * 16 + cr * 4 + r;
          float v = acc[mi][ni][r] + bv;
          if (EPI == 2) v = fmaxf(v, 0.f);
          const int ch = (col >> 3) ^ (loc & 7);
          Cs[loc * 128 + ch * 8 + (col & 7)] = f2bf(v);
        }
    }
    __syncthreads();
    const int lr = tid >> 4, lc = tid & 15;
#pragma unroll
    for (int pp = 0; pp < 4; ++pp) {
      const int loc = pp * 16 + lr;
      const int grow = m0 + loc;
      const short8v vv = *(const short8v*)&Cs[loc * 128 + ((lc ^ (loc & 7)) * 8)];
      if (grow < M) {
        if (VHM) {
          const int col = n0 + lc * 8;
          const int bb = grow >= kS ? 1 : 0;
          const int ss = grow - bb * kS;
          const int hh = col >> 5;
          *(short8v*)((unsigned short*)Cp +
                      (((size_t)(bb * kH + hh) * kS + ss) * kDh + (col & 31))) = vv;
        } else {
          *(short8v*)((unsigned short*)Cp + (size_t)grow * N + n0 + lc * 8) = vv;
        }
      }
    }
    __syncthreads();
  } else {
#pragma unroll
    for (int ni = 0; ni < 4; ++ni) {
      const int col = n0 + wc * 64 + ni * 16 + cc;
      if (col >= N) continue;
      const float bv = bias[col];
#pragma unroll
      for (int mi = 0; mi < MI; ++mi) {
#pragma unroll
        for (int r = 0; r < 4; ++r) {
          const int row = m0 + wr * (MI * 16) + mi * 16 + cr * 4 + r;
          if (row >= M) continue;
          ((float*)Cp)[(size_t)row * N + col] = acc[mi][ni][r] + bv;
        }
      }
    }
  }
}

// generic single-GEMM wrapper (used for aob)
template <int EPI, bool OBF, bool VHM>
__global__ __launch_bounds__(256) void mfma_gemm(const unsigned short* __restrict__ A,
                                                 const unsigned short* __restrict__ Bt,
                                                 const float* __restrict__ bias,
                                                 void* __restrict__ Cp,
                                                 int M, int N, int K) {
  __shared__ unsigned short smem[2 * 128 * 32];
  gemm_body<EPI, OBF, VHM>(A, Bt, bias, Cp, M, N, K, blockIdx.x, blockIdx.y, smem);
}

// merged value+oa GEMM: grid (5, mt64). bx<2 -> value (bf16 head-major),
// bx>=2 -> oa (f32).
__global__ __launch_bounds__(256) void qkvoa_gemm(const unsigned short* __restrict__ xb,
                                                  const unsigned short* __restrict__ Wvt,
                                                  const float* __restrict__ bval,
                                                  unsigned short* __restrict__ value,
                                                  const unsigned short* __restrict__ qb,
                                                  const unsigned short* __restrict__ Wct,
                                                  const float* __restrict__ bcomb,
                                                  float* __restrict__ oa,
                                                  int M) {
  __shared__ unsigned short smem[2 * 128 * 32];
  if (blockIdx.x < 2) {
    gemm_body<0, true, true>(xb, Wvt, bval, value, M, 256, 256, blockIdx.x, blockIdx.y, smem);
  } else {
    gemm_body<0, false, false>(qb, Wct, bcomb, oa, M, 288, 256, blockIdx.x - 2, blockIdx.y, smem);
  }
}

// ---------------- fused FFN v4 (PROVEN BEST, 59.3 us) -----------------------
__global__ __launch_bounds__(256) void ffn_fused(const unsigned short* __restrict__ Ain,
                                                 const unsigned short* __restrict__ W1t,
                                                 const unsigned short* __restrict__ W2t,
                                                 const float* __restrict__ b1,
                                                 const float* __restrict__ b2,
                                                 unsigned short* __restrict__ Cp,
                                                 int M) {
  __shared__ unsigned short W1s[2][64 * 256];  // 2 x 32 KB, [kk][row][32] swizzled
  __shared__ unsigned short Ps[2 * 64 * 32];   // 8 KB, [kb][row(m)][32] swizzled
  const int tid = threadIdx.x;
  const int w = tid >> 6, lane = tid & 63;
  const int m0 = blockIdx.x * 64;
  const int cr = lane >> 4, cc = lane & 15;

  short8v areg[8];
  {
    int grow = m0 + w * 16 + cc;
    grow = grow < M ? grow : M - 1;
    const unsigned short* ap = Ain + (size_t)grow * 256 + cr * 8;
#pragma unroll
    for (int kk = 0; kk < 8; ++kk) areg[kk] = *(const short8v*)(ap + kk * 32);
  }

  auto stage_w1 = [&](int jt, int buf) {
    const unsigned short* src = W1t + (size_t)jt * 64 * 256;
#pragma unroll
    for (int it = 0; it < 8; ++it) {
      const int idx = it * 256 + tid;      // 16B-chunk id, 0..2047
      const int kk = idx >> 8;
      const int row = (idx >> 2) & 63;
      const int sl = idx & 3;
      const int ssl = sl ^ ((row >> 1) & 3);
      gload_lds16(src + (size_t)row * 256 + kk * 32 + ssl * 8, &W1s[buf][idx * 8]);
    }
  };

  f32x4 acc[4][4] = {};  // [mi][ni]: rows mi*16+cr*4+r, cols w*64+ni*16+cc

  stage_w1(0, 0);
  __syncthreads();  // W1s[0] ready

  for (int jt = 0; jt < 16; ++jt) {
    const int buf = jt & 1;
    if (jt < 15) stage_w1(jt + 1, buf ^ 1);  // async prefetch, overlaps stage 1

    // hoist this jt's W2 fragments into registers (independent of LDS)
    short8v w2f[8];
#pragma unroll
    for (int kk2 = 0; kk2 < 2; ++kk2)
#pragma unroll
      for (int ni = 0; ni < 4; ++ni)
        w2f[kk2 * 4 + ni] = *(const short8v*)(W2t +
            (size_t)(w * 64 + ni * 16 + cc) * 1024 + jt * 64 + kk2 * 32 + cr * 8);

    // ---- stage 1: p1[ni] = sum_kk mfma(w1frag, areg)  (reg = ffn, cc = m)
    f32x4 p1[4] = {};
#pragma unroll
    for (int kk = 0; kk < 8; ++kk) {
#pragma unroll
      for (int ni = 0; ni < 4; ++ni) {
        const int row = ni * 16 + cc;
        const short8v wv = *(const short8v*)
            &W1s[buf][kk * 2048 + row * 32 + ((cr ^ ((row >> 1) & 3)) * 8)];
        p1[ni] = __builtin_amdgcn_mfma_f32_16x16x32_bf16(wv, areg[kk], p1[ni], 0, 0, 0);
      }
    }
    // bias + relu + bf16-pack; lane holds P[m=w*16+cc][ffn=ni*16+cr*4+r]
    {
      const int row = w * 16 + cc;
      const int rsw = (row >> 1) & 3;
#pragma unroll
      for (int ni = 0; ni < 4; ++ni) {
        const float4 bv = *(const float4*)&b1[jt * 64 + ni * 16 + cr * 4];
        const unsigned int u0 =
            (unsigned)f2bf(fmaxf(p1[ni][0] + bv.x, 0.f)) |
            ((unsigned)f2bf(fmaxf(p1[ni][1] + bv.y, 0.f)) << 16);
        const unsigned int u1 =
            (unsigned)f2bf(fmaxf(p1[ni][2] + bv.z, 0.f)) |
            ((unsigned)f2bf(fmaxf(p1[ni][3] + bv.w, 0.f)) << 16);
        const int kb = ni >> 1;
        const int slot = (ni & 1) * 2 + (cr >> 1);
        uint2v* dst = (uint2v*)&Ps[kb * 2048 + row * 32 + ((slot ^ rsw) * 8) + (cr & 1) * 4];
        *dst = (uint2v){u0, u1};
      }
    }
    __syncthreads();  // Ps visible; drains W1 prefetch (overlapped stage 1)

    // ---- stage 2: acc += P @ W2 (W2 frags already in registers)
#pragma unroll
    for (int kk2 = 0; kk2 < 2; ++kk2) {
      short8v pf[4];
#pragma unroll
      for (int mi = 0; mi < 4; ++mi) {
        const int row = mi * 16 + cc;
        pf[mi] = *(const short8v*)
            &Ps[kk2 * 2048 + row * 32 + ((cr ^ ((row >> 1) & 3)) * 8)];
      }
#pragma unroll
      for (int ni = 0; ni < 4; ++ni) {
#pragma unroll
        for (int mi = 0; mi < 4; ++mi)
          acc[mi][ni] = __builtin_amdgcn_mfma_f32_16x16x32_bf16(pf[mi], w2f[kk2 * 4 + ni],
                                                               acc[mi][ni], 0, 0, 0);
      }
    }
    __syncthreads();  // Ps reads done before next jt's writes
  }

  // epilogue: stage bf16 C tile into W1s[0] (reuse), then full-line stores
  unsigned short* Cs = &W1s[0][0];
#pragma unroll
  for (int ni = 0; ni < 4; ++ni) {
    const int col = w * 64 + ni * 16 + cc;
    const float bv = b2[col];
#pragma unroll
    for (int mi = 0; mi < 4; ++mi)
#pragma unroll
      for (int r = 0; r < 4; ++r) {
        const int row = mi * 16 + cr * 4 + r;
        const float v = acc[mi][ni][r] + bv;
        Cs[row * 256 + (((col >> 3) ^ (row & 7)) * 8) + (col & 7)] = f2bf(v);
      }
  }
  __syncthreads();
#pragma unroll
  for (int it = 0; it < 8; ++it) {
    const int row = it * 8 + (tid >> 5);
    const int grow = m0 + row;
    const int ch = tid & 31;
    const short8v vv = *(const short8v*)&Cs[row * 256 + ((ch ^ (row & 7)) * 8)];
    if (grow < M) *(short8v*)(Cp + (size_t)grow * 256 + ch * 8) = vv;
  }
}

// ---------------- deformable sampling (value head-major bf16 -> sv bf16) ----
// Block->query mapping reordered to (b, h, s)-major with a bijective chunked
// XCD swizzle: each block's 64 queries come from ONE (b,h) slice (0.84 MB
// head-major value footprint), and consecutive swizzled blocks on an XCD walk
// the same slice -> per-XCD L2 working set ~1-2 slices instead of the whole
// 13.4 MB value tensor. Math identical to R15.
__device__ __forceinline__ void acc2u(f32x2* acc, unsigned u, int i, float m) {
  f32x2 v;
  v.x = __builtin_bit_cast(float, u << 16);
  v.y = __builtin_bit_cast(float, u & 0xFFFF0000u);
  acc[i] += m * v;
}
__device__ __forceinline__ void acc_corner(f32x2* acc, uint4 q, float m) {
  acc2u(acc, q.x, 0, m);
  acc2u(acc, q.y, 1, m);
  acc2u(acc, q.z, 2, m);
  acc2u(acc, q.w, 3, m);
}

__global__ __launch_bounds__(256) void sample_kernel(const unsigned short* __restrict__ value,
                                                     const float* __restrict__ oa,
                                                     const float* __restrict__ refp,
                                                     unsigned short* __restrict__ out) {
  const int tid = threadIdx.x;
  const int sub = tid >> 2;    // 64 queries per block
  const int lane = tid & 3;    // 4 lanes x 8 channels

  // bijective chunked XCD swizzle (8 XCDs, round-robin dispatch)
  const int nwg = gridDim.x;
  const int qch = nwg >> 3, rch = nwg & 7;
  const int xcd = blockIdx.x & 7, jj = blockIdx.x >> 3;
  const int wg = (xcd < rch ? xcd * (qch + 1) : rch * (qch + 1) + (xcd - rch) * qch) + jj;

  // (b,h,s)-major query index: qi = ((b*8+h)*kS + s)
  const int qi = wg * 64 + sub;
  if (qi >= kB * kH * kS) return;
  const int bh = qi / kS;          // b*8+h
  const int s = qi - bh * kS;
  const int b = bh >> 3, h = bh & 7;
  const int bs = b * kS + s;       // row in oa / out

  const float* op = oa + (size_t)bs * 288 + h * 36;
  const float* al = op + 24;
  float w[12];
  float mx = -1e30f;
#pragma unroll
  for (int i = 0; i < 12; ++i) { w[i] = al[i]; mx = fmaxf(mx, w[i]); }
  float sum = 0.f;
#pragma unroll
  for (int i = 0; i < 12; ++i) { w[i] = __expf(w[i] - mx); sum += w[i]; }
  const float inv = 1.f / sum;
#pragma unroll
  for (int i = 0; i < 12; ++i) w[i] *= inv;

  const float* rp = refp + (size_t)bs * (kL * 2);
  const unsigned short* vbase = value + ((size_t)bh * kS) * kDh + lane * 8;

  const int LH[3] = {100, 50, 25}, LW[3] = {100, 50, 25}, LS[3] = {0, 10000, 12500};
  f32x2 acc[4] = {};
#pragma unroll
  for (int l = 0; l < 3; ++l) {
    const int Wi = LW[l], Hi = LH[l];
    const float Wl = (float)Wi, Hl = (float)Hi;
    const float rxw = rp[l * 2 + 0] * Wl - 0.5f;
    const float ryh = rp[l * 2 + 1] * Hl - 0.5f;
    const unsigned short* lvl = vbase + (size_t)LS[l] * kDh;
#pragma unroll
    for (int p = 0; p < 4; ++p) {
      const float ox = op[l * 8 + p * 2 + 0], oy = op[l * 8 + p * 2 + 1];
      const float xf = rxw + ox;
      const float yf = ryh + oy;
      const float x0f = floorf(xf), y0f = floorf(yf);
      const float fx = xf - x0f, fy = yf - y0f;
      const int x0 = (int)x0f, y0 = (int)y0f;
      const int x1 = x0 + 1, y1 = y0 + 1;
      const bool vx0 = (unsigned)x0 < (unsigned)Wi;
      const bool vx1 = (unsigned)x1 < (unsigned)Wi;
      const bool vy0 = (unsigned)y0 < (unsigned)Hi;
      const bool vy1 = (unsigned)y1 < (unsigned)Hi;
      const int cx0 = min(max(x0, 0), Wi - 1), cx1 = min(max(x1, 0), Wi - 1);
      const int cy0 = min(max(y0, 0), Hi - 1), cy1 = min(max(y1, 0), Hi - 1);
      const float aw = w[l * 4 + p];
      const float ax = aw * fx, a0 = aw - ax;
      const float w00 = a0 - a0 * fy, w10 = a0 * fy;
      const float w01 = ax - ax * fy, w11 = ax * fy;
      const float m00 = (vx0 && vy0) ? w00 : 0.f;
      const float m01 = (vx1 && vy0) ? w01 : 0.f;
      const float m10 = (vx0 && vy1) ? w10 : 0.f;
      const float m11 = (vx1 && vy1) ? w11 : 0.f;
      const int ry0 = cy0 * Wi, ry1 = cy1 * Wi;
      const uint4 q00 = *(const uint4*)(lvl + (size_t)(ry0 + cx0) * kDh);
      const uint4 q01 = *(const uint4*)(lvl + (size_t)(ry0 + cx1) * kDh);
      const uint4 q10 = *(const uint4*)(lvl + (size_t)(ry1 + cx0) * kDh);
      const uint4 q11 = *(const uint4*)(lvl + (size_t)(ry1 + cx1) * kDh);
      acc_corner(acc, q00, m00);
      acc_corner(acc, q01, m01);
      acc_corner(acc, q10, m10);
      acc_corner(acc, q11, m11);
    }
  }
  unsigned short r[8];
#pragma unroll
  for (int i = 0; i < 4; ++i) {
    r[2 * i] = f2bf(acc[i].x);
    r[2 * i + 1] = f2bf(acc[i].y);
  }
  *(short8v*)(out + (size_t)bs * kD + h * kDh + lane * 8) = *(const short8v*)r;
}

// ------------- fused residual + layernorm: out = LN(X + Ab) -----------------
template <int WB>
__global__ __launch_bounds__(256) void lnres_kernel(const float* __restrict__ X,
                                                    const unsigned short* __restrict__ Ab,
                                                    const float* __restrict__ g,
                                                    const float* __restrict__ be,
                                                    float* __restrict__ out,
                                                    unsigned short* __restrict__ outb,
                                                    int rows) {
  const int wid = threadIdx.x >> 6, lane = threadIdx.x & 63;
  const int row = blockIdx.x * 4 + wid;
  if (row >= rows) return;
  const float4 v = ((const float4*)(X + (size_t)row * kD))[lane];
  const ushort4 a4 = ((const ushort4*)(Ab + (size_t)row * kD))[lane];
  float4 t;
  t.x = v.x + bf2f(a4.x);
  t.y = v.y + bf2f(a4.y);
  t.z = v.z + bf2f(a4.z);
  t.w = v.w + bf2f(a4.w);
  float s = t.x + t.y + t.z + t.w;
  float sq = t.x * t.x + t.y * t.y + t.z * t.z + t.w * t.w;
#pragma unroll
  for (int o = 1; o < 64; o <<= 1) {
    s += __shfl_xor(s, o);
    sq += __shfl_xor(sq, o);
  }
  const float mean = s * (1.f / kD);
  const float var = sq * (1.f / kD) - mean * mean;
  const float rs = rsqrtf(var + 1e-5f);
  const float4 gg = ((const float4*)g)[lane];
  const float4 bb = ((const float4*)be)[lane];
  float4 o4;
  o4.x = (t.x - mean) * rs * gg.x + bb.x;
  o4.y = (t.y - mean) * rs * gg.y + bb.y;
  o4.z = (t.z - mean) * rs * gg.z + bb.z;
  o4.w = (t.w - mean) * rs * gg.w + bb.w;
  ((float4*)(out + (size_t)row * kD))[lane] = o4;
  if (WB) {
    ((ushort4*)(outb + (size_t)row * kD))[lane] =
        make_ushort4(f2bf(o4.x), f2bf(o4.y), f2bf(o4.z), f2bf(o4.w));
  }
}

}  // namespace

extern "C" void kernel_launch(void* const* d_in, const int* in_sizes, int n_in,
                              void* d_out, int out_size, void* d_ws, size_t ws_size,
                              hipStream_t stream) {
  const float* x      = (const float*)d_in[0];
  const float* pos    = (const float*)d_in[1];
  const float* refp   = (const float*)d_in[2];
  const float* W_off  = (const float*)d_in[3];
  const float* b_off  = (const float*)d_in[4];
  const float* W_attn = (const float*)d_in[5];
  const float* b_attn = (const float*)d_in[6];
  const float* W_val  = (const float*)d_in[7];
  const float* b_val  = (const float*)d_in[8];
  const float* W_out  = (const float*)d_in[9];
  const float* b_out  = (const float*)d_in[10];
  const float* g1     = (const float*)d_in[11];
  const float* be1    = (const float*)d_in[12];
  const float* W1     = (const float*)d_in[13];
  const float* b1     = (const float*)d_in[14];
  const float* W2     = (const float*)d_in[15];
  const float* b2     = (const float*)d_in[16];
  const float* g2     = (const float*)d_in[17];
  const float* be2    = (const float*)d_in[18];
  float* outp = (float*)d_out;

  // ---- workspace layout (bytes), peak ~139 MB.
  char* ws = (char*)d_ws;
  unsigned short* Wvt = (unsigned short*)(ws + 0);        // 256x256
  unsigned short* Wot = (unsigned short*)(ws + 131072);   // 256x256
  unsigned short* Wct = (unsigned short*)(ws + 262144);   // 384x256 (288 used)
  float* bcomb        = (float*)(ws + 262144 + 288 * 512);
  unsigned short* W1t = (unsigned short*)(ws + 458752);   // 1024x256
  unsigned short* W2t = (unsigned short*)(ws + 983040);   // 256x1024
  const size_t MDb = (size_t)kM * kD * 2;                 // 13,440,000 B
  char* regA = ws + 1507328;                 // xb -> aob
  char* regB = regA + MDb;                   // qb -> f2b
  char* regC = regB + MDb;                   // value+oa -> h1+h1b
  char* regG = regC + 43680000;              // sv (bf16)

  unsigned short* xb    = (unsigned short*)regA;
  unsigned short* aob   = (unsigned short*)regA;  // attn-out bf16 (xb dead)
  unsigned short* qb    = (unsigned short*)regB;
  unsigned short* f2b   = (unsigned short*)regB;  // ffn-out bf16 (qb dead)
  unsigned short* value = (unsigned short*)regC;  // head-major [B,H,S,Dh]
  float* oa   = (float*)(regC + MDb);             // [M][288]
  float* h1   = (float*)regC;                     // f32 (value+oa dead)
  unsigned short* h1b = (unsigned short*)(regC + (size_t)kM * kD * 4);
  unsigned short* sv  = (unsigned short*)regG;    // sampled attn (bf16)

  const dim3 blk(256);
  const int mt64 = (kM + 63) / 64;  // 411
  const int n4 = kM * kD / 4;

  // 0. all weight transpose+cast in ONE launch
  wprep_all<<<(729088 + 255) / 256, blk, 0, stream>>>(W_val, W_out, W_off, W_attn,
                                                      b_off, b_attn, W1, W2,
                                                      Wvt, Wot, Wct, bcomb, W1t, W2t);
  // 1. xb = bf16(x); qb = bf16(x + pos)
  prep_kernel<<<(n4 + 255) / 256, blk, 0, stream>>>((const float4*)x, (const float4*)pos,
                                                    (ushort4*)xb, (ushort4*)qb, n4);
  // 2+3. value AND oa in ONE launch (grid 5 x 411)
  qkvoa_gemm<<<dim3(5, mt64), blk, 0, stream>>>(xb, Wvt, b_val, value,
                                                qb, Wct, bcomb, oa, kM);
  // 4. softmax + deformable sampling -> sv (bf16), (b,h,s)-major + XCD swizzle
  sample_kernel<<<(kB * kS * kH + 63) / 64, blk, 0, stream>>>(value, oa, refp, sv);
  // 5. aob = sv @ Wo + b_out (bf16; residual deferred to lnres)
  mfma_gemm<0, true, false><<<dim3(2, mt64), blk, 0, stream>>>(sv, Wot, b_out, aob,
                                                               kM, 256, 256);
  // 6. h1 = LN(x + aob) (f32 + bf16)
  lnres_kernel<1><<<(kM + 3) / 4, blk, 0, stream>>>(x, aob, g1, be1, h1, h1b, kM);
  // 7. f2b = relu(h1b @ W1 + b1) @ W2 + b2 (fused FFN v4, bf16)
  ffn_fused<<<mt64, blk, 0, stream>>>(h1b, W1t, W2t, b1, b2, f2b, kM);
  // 8. out = LN(h1 + f2b)
  lnres_kernel<0><<<(kM + 3) / 4, blk, 0, stream>>>(h1, f2b, g2, be2, outp, nullptr, kM);
}